// Round 1
// baseline (295.225 us; speedup 1.0000x reference)
//
#include <hip/hip_runtime.h>
#include <hip/hip_bf16.h>

typedef __hip_bfloat16 bf16;
typedef float f32x4 __attribute__((ext_vector_type(4)));
typedef short s16x8 __attribute__((ext_vector_type(8)));
typedef short s16x4 __attribute__((ext_vector_type(4)));

typedef const __attribute__((address_space(1))) void* as1cvp;
typedef __attribute__((address_space(3))) void* as3vp;

__device__ __forceinline__ unsigned short f2bf(float f) {
  unsigned u = __float_as_uint(f);
  u += 0x7FFFu + ((u >> 16) & 1u);   // RNE
  return (unsigned short)(u >> 16);
}
__device__ __forceinline__ float bf2f(short s) {
  return __uint_as_float(((unsigned)(unsigned short)s) << 16);
}

// ---------- cast fp32 -> bf16, 8 elems/thread ----------
__global__ __launch_bounds__(256) void cast_f32_to_bf16(const float* __restrict__ in,
                                                        unsigned short* __restrict__ out,
                                                        int n8) {
  int i = blockIdx.x * 256 + threadIdx.x;
  if (i >= n8) return;
  long base = (long)i * 8;
  f32x4 v0 = *(const f32x4*)&in[base];
  f32x4 v1 = *(const f32x4*)&in[base + 4];
  s16x8 o;
  o[0] = (short)f2bf(v0[0]); o[1] = (short)f2bf(v0[1]);
  o[2] = (short)f2bf(v0[2]); o[3] = (short)f2bf(v0[3]);
  o[4] = (short)f2bf(v1[0]); o[5] = (short)f2bf(v1[1]);
  o[6] = (short)f2bf(v1[2]); o[7] = (short)f2bf(v1[3]);
  *(s16x8*)&out[base] = o;
}

// ---------- m97-style 128x128 bf16 GEMM: C[m,n] = sum_k A[m,k]*Bt[n,k] ----------
// 4 waves, 64x64 per wave (4x4 frags of 16x16x32), BK=32, global_load_lds width 16.
template<bool OUTF32>
__global__ __launch_bounds__(256) void gemm_bt_128(
    const bf16* __restrict__ A, int lda,
    const bf16* __restrict__ Bt, int ldb, long btStride, int rowsPerB,
    void* __restrict__ Cv, int ldc,
    const float* __restrict__ bias, int K)
{
  __shared__ bf16 As[128 * 32];
  __shared__ bf16 Bs[128 * 32];

  const int tid  = threadIdx.x;
  const int wave = tid >> 6;
  const int lane = tid & 63;
  const int bm = blockIdx.y * 128;
  const int bn = blockIdx.x * 128;

  const bf16* Bp = Bt + (btStride ? (long)(bm / rowsPerB) * btStride : 0);

  // staging: 2 issues per matrix per K-step; each thread 16B
  const int srow = wave * 16 + (lane >> 2);
  const int scol = (lane & 3) * 8;
  const bf16* Ag = A  + (long)(bm + srow) * lda + scol;
  const bf16* Bg = Bp + (long)(bn + srow) * ldb + scol;
  const long a64 = (long)64 * lda;
  const long b64 = (long)64 * ldb;
  bf16* AsW = As + wave * 512;   // wave-uniform LDS base (+lane*16B implicit)
  bf16* BsW = Bs + wave * 512;

  const int frow = lane & 15;
  const int fk   = (lane >> 4) * 8;
  const int wr = (wave >> 1) * 64;
  const int wc = (wave & 1) * 64;

  f32x4 acc[4][4] = {};

  for (int k0 = 0; k0 < K; k0 += 32) {
    __builtin_amdgcn_global_load_lds((as1cvp)(Ag),       (as3vp)(AsW),        16, 0, 0);
    __builtin_amdgcn_global_load_lds((as1cvp)(Ag + a64), (as3vp)(AsW + 2048), 16, 0, 0);
    __builtin_amdgcn_global_load_lds((as1cvp)(Bg),       (as3vp)(BsW),        16, 0, 0);
    __builtin_amdgcn_global_load_lds((as1cvp)(Bg + b64), (as3vp)(BsW + 2048), 16, 0, 0);
    Ag += 32; Bg += 32;
    __syncthreads();

    s16x8 af[4], bfv[4];
#pragma unroll
    for (int i = 0; i < 4; ++i)
      af[i] = *(const s16x8*)&As[(wr + i * 16 + frow) * 32 + fk];
#pragma unroll
    for (int j = 0; j < 4; ++j)
      bfv[j] = *(const s16x8*)&Bs[(wc + j * 16 + frow) * 32 + fk];
#pragma unroll
    for (int i = 0; i < 4; ++i)
#pragma unroll
      for (int j = 0; j < 4; ++j)
        acc[i][j] = __builtin_amdgcn_mfma_f32_16x16x32_bf16(af[i], bfv[j], acc[i][j], 0, 0, 0);
    __syncthreads();
  }

  // C/D layout: col = lane&15, row = (lane>>4)*4 + reg   [m89-verified]
  const int crow = bm + wr + (lane >> 4) * 4;
  const int ccol = bn + wc + (lane & 15);
  if (OUTF32) {
    float* C = (float*)Cv;
#pragma unroll
    for (int j = 0; j < 4; ++j) {
      const int col = ccol + j * 16;
      const float bs = bias ? bias[col] : 0.0f;
#pragma unroll
      for (int i = 0; i < 4; ++i)
#pragma unroll
        for (int r = 0; r < 4; ++r)
          C[(long)(crow + i * 16 + r) * ldc + col] = acc[i][j][r] + bs;
    }
  } else {
    unsigned short* C = (unsigned short*)Cv;
#pragma unroll
    for (int j = 0; j < 4; ++j) {
      const int col = ccol + j * 16;
#pragma unroll
      for (int i = 0; i < 4; ++i)
#pragma unroll
        for (int r = 0; r < 4; ++r)
          C[(long)(crow + i * 16 + r) * ldc + col] = f2bf(acc[i][j][r]);
    }
  }
}

// ---------- kv partials: part[ck][bh][d][e] = sum_{n in chunk} k[n,d]*v[n,e] ----------
__global__ __launch_bounds__(256) void kv_partial_kernel(const bf16* __restrict__ qkv,
                                                         float* __restrict__ part) {
  __shared__ bf16 ks[256 * 64];
  __shared__ bf16 vs[256 * 64];
  const int bh = blockIdx.x;      // b*16 + h
  const int ck = blockIdx.y;      // n-chunk of 256
  const int b = bh >> 4, h = bh & 15;
  const int t = threadIdx.x;

  const long rowbase = (long)(b * 4096 + ck * 256) * 3072;
  const bf16* kg = qkv + rowbase + 1024 + h * 64;
  const bf16* vg = qkv + rowbase + 2048 + h * 64;
  const int lr = t >> 3;          // 0..31
  const int lc = (t & 7) * 8;
#pragma unroll
  for (int it = 0; it < 8; ++it) {
    const int r = lr + it * 32;
    *(s16x8*)&ks[r * 64 + lc] = *(const s16x8*)&kg[(long)r * 3072 + lc];
    *(s16x8*)&vs[r * 64 + lc] = *(const s16x8*)&vg[(long)r * 3072 + lc];
  }
  __syncthreads();

  const int d0 = (t >> 4) * 4;
  const int e0 = (t & 15) * 4;
  f32x4 acc[4] = {};
  for (int n = 0; n < 256; ++n) {
    s16x4 kd = *(const s16x4*)&ks[n * 64 + d0];
    s16x4 ve = *(const s16x4*)&vs[n * 64 + e0];
    float kf0 = bf2f(kd[0]), kf1 = bf2f(kd[1]), kf2 = bf2f(kd[2]), kf3 = bf2f(kd[3]);
    f32x4 vf;
    vf[0] = bf2f(ve[0]); vf[1] = bf2f(ve[1]); vf[2] = bf2f(ve[2]); vf[3] = bf2f(ve[3]);
#pragma unroll
    for (int j = 0; j < 4; ++j) {
      acc[0][j] += kf0 * vf[j];
      acc[1][j] += kf1 * vf[j];
      acc[2][j] += kf2 * vf[j];
      acc[3][j] += kf3 * vf[j];
    }
  }
  float* pb = part + (((long)ck * 64 + bh) << 12);
#pragma unroll
  for (int i = 0; i < 4; ++i)
    *(f32x4*)&pb[(d0 + i) * 64 + e0] = acc[i];
}

// ---------- reduce partials, apply scale, store TRANSPOSED: kvT[bh][e][d] ----------
__global__ __launch_bounds__(256) void kv_reduce_kernel(const float* __restrict__ part,
                                                        float* __restrict__ kvT) {
  const int idx = blockIdx.x * 256 + threadIdx.x;  // bh*4096 + d*64 + e
  float s = 0.0f;
#pragma unroll
  for (int ck = 0; ck < 16; ++ck) s += part[(long)ck * 262144 + idx];
  s *= 0.125f;                                      // D^-0.5, D=64
  const int bh = idx >> 12;
  const int d = (idx >> 6) & 63;
  const int e = idx & 63;
  kvT[((long)bh << 12) + e * 64 + d] = s;
}

// ---------- Mt_b[o, h*64+d] = sum_e Wo[o, h*64+e] * kv[b,h,d,e], bf16 out ----------
__global__ __launch_bounds__(256) void mt_kernel(const float* __restrict__ kvT,
                                                 const float* __restrict__ Wo,
                                                 unsigned short* __restrict__ Mt) {
  __shared__ float kvs[64 * 64];   // [e][d]
  __shared__ float wos[64 * 68];   // [o][e], padded stride 68 (bank spread)
  const int oblk = blockIdx.x, h = blockIdx.y, b = blockIdx.z;
  const int t = threadIdx.x;

  const float* kvp = kvT + (((long)b * 16 + h) << 12);
#pragma unroll
  for (int i = 0; i < 16; ++i) kvs[t + i * 256] = kvp[t + i * 256];
  {
    const int r = t >> 2;
    const int c0 = (t & 3) * 16;
    const float* wop = Wo + (long)(oblk * 64 + r) * 1024 + h * 64 + c0;
#pragma unroll
    for (int j = 0; j < 16; j += 4)
      *(f32x4*)&wos[r * 68 + c0 + j] = *(const f32x4*)&wop[j];
  }
  __syncthreads();

  const int o = t >> 2;
  const int d0 = (t & 3) * 16;
  f32x4 acc[4] = {};
  for (int e = 0; e < 64; ++e) {
    const float w = wos[o * 68 + e];
    const float* kr = &kvs[e * 64 + d0];
#pragma unroll
    for (int q = 0; q < 4; ++q) {
      f32x4 kv4 = *(const f32x4*)&kr[q * 4];
#pragma unroll
      for (int j = 0; j < 4; ++j) acc[q][j] += w * kv4[j];
    }
  }
  unsigned short* mp = Mt + (long)b * 1048576 + (long)(oblk * 64 + o) * 1024 + h * 64 + d0;
#pragma unroll
  for (int q = 0; q < 4; ++q)
#pragma unroll
    for (int j = 0; j < 4; ++j) mp[q * 4 + j] = f2bf(acc[q][j]);
}

extern "C" void kernel_launch(void* const* d_in, const int* in_sizes, int n_in,
                              void* d_out, int out_size, void* d_ws, size_t ws_size,
                              hipStream_t stream) {
  const float* x  = (const float*)d_in[0];
  const float* Wq = (const float*)d_in[1];
  const float* Wk = (const float*)d_in[2];
  const float* Wv = (const float*)d_in[3];
  const float* Wo = (const float*)d_in[4];
  const float* bo = (const float*)d_in[5];
  float* out = (float*)d_out;

  char* ws = (char*)d_ws;
  // layout (bytes):
  //   [0, 32M):    xb bf16 (16384x1024)  -- reused after QKV GEMM for part/kvT/Mt
  //   [0, 16M):      part fp32 [16][64][64][64]
  //   [16M, 17M):    kvT fp32 [64][64e][64d]
  //   [17.0M, 25.4M):Mt bf16 [4][1024][1024]
  //   [32M, 38M):  Wcat bf16 (3072x1024)
  //   [38M, 134M): qkv bf16 (16384x3072)
  bf16* xb    = (bf16*)(ws);
  float* part = (float*)(ws);
  float* kvT  = (float*)(ws + 16777216);
  unsigned short* Mt = (unsigned short*)(ws + 17825792);
  bf16* Wcat  = (bf16*)(ws + 33554432);
  bf16* qkv   = (bf16*)(ws + 39845888);

  // 1) casts
  cast_f32_to_bf16<<<8192, 256, 0, stream>>>(x, (unsigned short*)xb, 2097152);
  cast_f32_to_bf16<<<512, 256, 0, stream>>>(Wq, (unsigned short*)(Wcat), 131072);
  cast_f32_to_bf16<<<512, 256, 0, stream>>>(Wk, (unsigned short*)(Wcat + 1048576), 131072);
  cast_f32_to_bf16<<<512, 256, 0, stream>>>(Wv, (unsigned short*)(Wcat + 2097152), 131072);

  // 2) QKV GEMM: [16384,1024] x [3072,1024]^T -> qkv bf16 [16384,3072]
  gemm_bt_128<false><<<dim3(24, 128), 256, 0, stream>>>(
      xb, 1024, Wcat, 1024, 0L, 4096, (void*)qkv, 3072, nullptr, 1024);

  // 3) kv = scale * k^T v  (per b,h), via partials + reduce (deterministic)
  kv_partial_kernel<<<dim3(64, 16), 256, 0, stream>>>(qkv, part);
  kv_reduce_kernel<<<1024, 256, 0, stream>>>(part, kvT);

  // 4) Mt_b = (blockdiag(kv_b) . Wo^T)^T in B^T layout, bf16
  mt_kernel<<<dim3(16, 16, 4), 256, 0, stream>>>(kvT, Wo, Mt);

  // 5) out = q . Mt_b^T + bo   (fp32 out, per-batch B matrix)
  gemm_bt_128<true><<<dim3(8, 128), 256, 0, stream>>>(
      qkv, 3072, (const bf16*)Mt, 1024, 1048576L, 4096, (void*)out, 1024, bo, 1024);
}

// Round 2
// 243.756 us; speedup vs baseline: 1.2111x; 1.2111x over previous
//
#include <hip/hip_runtime.h>
#include <hip/hip_bf16.h>

typedef __hip_bfloat16 bf16;
typedef float f32x4 __attribute__((ext_vector_type(4)));
typedef short s16x8 __attribute__((ext_vector_type(8)));
typedef short s16x4 __attribute__((ext_vector_type(4)));

typedef const __attribute__((address_space(1))) void* as1cvp;
typedef __attribute__((address_space(3))) void* as3vp;

__device__ __forceinline__ unsigned short f2bf(float f) {
  unsigned u = __float_as_uint(f);
  u += 0x7FFFu + ((u >> 16) & 1u);   // RNE
  return (unsigned short)(u >> 16);
}
__device__ __forceinline__ float bf2f(short s) {
  return __uint_as_float(((unsigned)(unsigned short)s) << 16);
}

__device__ __forceinline__ void gpu_barrier() {
  asm volatile("" ::: "memory");
  __builtin_amdgcn_s_barrier();
  asm volatile("" ::: "memory");
}

// ---------- cast fp32 -> bf16, 8 elems/thread ----------
__global__ __launch_bounds__(256) void cast_f32_to_bf16(const float* __restrict__ in,
                                                        unsigned short* __restrict__ out,
                                                        int n8) {
  int i = blockIdx.x * 256 + threadIdx.x;
  if (i >= n8) return;
  long base = (long)i * 8;
  f32x4 v0 = *(const f32x4*)&in[base];
  f32x4 v1 = *(const f32x4*)&in[base + 4];
  s16x8 o;
  o[0] = (short)f2bf(v0[0]); o[1] = (short)f2bf(v0[1]);
  o[2] = (short)f2bf(v0[2]); o[3] = (short)f2bf(v0[3]);
  o[4] = (short)f2bf(v1[0]); o[5] = (short)f2bf(v1[1]);
  o[6] = (short)f2bf(v1[2]); o[7] = (short)f2bf(v1[3]);
  *(s16x8*)&out[base] = o;
}

// ================= 256x256 8-phase bf16 GEMM (T1+T2+T3+T4+T5) =================
// C[m,n] = sum_k A[m,k]*Bt[n,k].  8 waves (2M x 4N), BK=64, LDS 128 KiB dbuf.
// LDS swizzle: byte ^= ((row&7)<<4) applied on ds_read AND (inverse, same XOR)
// on the per-lane global source of global_load_lds (linear LDS dest).
template<bool OUTF32>
__global__ __launch_bounds__(512, 2) void gemm256(
    const bf16* __restrict__ A, int lda,
    const bf16* __restrict__ Bt, int ldb, long btStride, int rowsPerB,
    void* __restrict__ Cv, int ldc,
    const float* __restrict__ bias, int K, int mtiles)
{
  __shared__ char lds[131072];  // A: [buf0 32K][buf1 32K] ; B at +64K same layout

  const int nwg = gridDim.x;
  const int bid = blockIdx.x;
  const int wg  = (bid & 7) * (nwg >> 3) + (bid >> 3);  // XCD swizzle (nwg%8==0)
  const int bm = (wg % mtiles) * 256;
  const int bn = (wg / mtiles) * 256;

  const int tid  = threadIdx.x;
  const int wid  = tid >> 6;
  const int lane = tid & 63;
  const int wm = wid >> 2;        // 0..1
  const int wn = wid & 3;         // 0..3
  const int frow = lane & 15;
  const int fkb  = (lane >> 4) << 4;              // k-chunk byte offset (0,16,32,48)
  const unsigned xorv = (unsigned)((lane & 7) << 4);

  const bf16* Bp = Bt + (btStride ? (long)(bm / rowsPerB) * btStride : 0);

  // staging source coords: LDS linear pos p -> global pos q = p ^ (((p>>7)&7)<<4)
  const int q0 = (tid * 16) ^ (((tid >> 3) & 7) << 4);
  const int q1 = (8192 + tid * 16) ^ (((tid >> 3) & 7) << 4);
  const int srow0 = q0 >> 7, scol0 = (q0 & 127) >> 1;
  const int srow1 = q1 >> 7, scol1 = (q1 & 127) >> 1;   // 64..127
  const bf16* ag0 = A  + (long)(bm + srow0) * lda + scol0;
  const bf16* ag1 = A  + (long)(bm + srow1) * lda + scol1;
  const bf16* bg0 = Bp + (long)(bn + srow0) * ldb + scol0;
  const bf16* bg1 = Bp + (long)(bn + srow1) * ldb + scol1;

#define STAGE_A(buf, half, kk) do {                                                  \
    __builtin_amdgcn_global_load_lds((as1cvp)(ag0 + (long)(half)*128*lda + (kk)),    \
        (as3vp)(lds + (buf)*32768 + (half)*16384 + wid*1024), 16, 0, 0);             \
    __builtin_amdgcn_global_load_lds((as1cvp)(ag1 + (long)(half)*128*lda + (kk)),    \
        (as3vp)(lds + (buf)*32768 + (half)*16384 + 8192 + wid*1024), 16, 0, 0);      \
  } while (0)
#define STAGE_B(buf, half, kk) do {                                                  \
    __builtin_amdgcn_global_load_lds((as1cvp)(bg0 + (long)(half)*128*ldb + (kk)),    \
        (as3vp)(lds + 65536 + (buf)*32768 + (half)*16384 + wid*1024), 16, 0, 0);     \
    __builtin_amdgcn_global_load_lds((as1cvp)(bg1 + (long)(half)*128*ldb + (kk)),    \
        (as3vp)(lds + 65536 + (buf)*32768 + (half)*16384 + 8192 + wid*1024), 16, 0, 0); \
  } while (0)

  const unsigned paBase = (unsigned)((wm * 64 + frow) * 128 + fkb);
  const unsigned pbBase = (unsigned)(((wn & 1) * 64 + frow) * 128 + fkb);
  const unsigned bHalf  = (unsigned)((wn >> 1) * 16384);

#define RD_A(dst, cur, Mh, mi, kh)                                                   \
  dst = *(const s16x8*)(lds + (cur)*32768 + (Mh)*16384 +                             \
                        ((paBase + (mi)*2048u + (kh)*64u) ^ xorv))
#define RD_B(dst, cur, nj, kh)                                                       \
  dst = *(const s16x8*)(lds + 65536 + (cur)*32768 + bHalf +                          \
                        ((pbBase + (nj)*2048u + (kh)*64u) ^ xorv))

#define MFMA_QUAD(Mh, Nh)                                                            \
  __builtin_amdgcn_s_setprio(1);                                                     \
  _Pragma("unroll")                                                                  \
  for (int mi = 0; mi < 4; ++mi) {                                                   \
    acc[(Mh)*4+mi][(Nh)*2+0] = __builtin_amdgcn_mfma_f32_16x16x32_bf16(              \
        a[mi][0], b[(Nh)*2+0][0], acc[(Mh)*4+mi][(Nh)*2+0], 0, 0, 0);                \
    acc[(Mh)*4+mi][(Nh)*2+0] = __builtin_amdgcn_mfma_f32_16x16x32_bf16(              \
        a[mi][1], b[(Nh)*2+0][1], acc[(Mh)*4+mi][(Nh)*2+0], 0, 0, 0);                \
    acc[(Mh)*4+mi][(Nh)*2+1] = __builtin_amdgcn_mfma_f32_16x16x32_bf16(              \
        a[mi][0], b[(Nh)*2+1][0], acc[(Mh)*4+mi][(Nh)*2+1], 0, 0, 0);                \
    acc[(Mh)*4+mi][(Nh)*2+1] = __builtin_amdgcn_mfma_f32_16x16x32_bf16(              \
        a[mi][1], b[(Nh)*2+1][1], acc[(Mh)*4+mi][(Nh)*2+1], 0, 0, 0);                \
  }                                                                                  \
  __builtin_amdgcn_s_setprio(0);

  f32x4 acc[8][4] = {};
  s16x8 a[4][2], b[4][2];
  const int NT = K >> 6;

  // ---- prologue: 7 half-tiles in stream order, then vmcnt(6) -> K-tile 0 landed
  STAGE_A(0, 0, 0); STAGE_B(0, 0, 0); STAGE_A(0, 1, 0); STAGE_B(0, 1, 0);
  {
    const int kk = (NT > 1) ? 64 : 0;
    STAGE_A(1, 0, kk); STAGE_B(1, 0, kk); STAGE_A(1, 1, kk);
  }
  asm volatile("s_waitcnt vmcnt(6)" ::: "memory");
  gpu_barrier();

  for (int t = 0; t < NT; ++t) {
    const int cur = t & 1, nxt = cur ^ 1;
    const int k1 = ((t + 1 < NT) ? (t + 1) : 0) * 64;  // dead loads clamp to k=0
    const int k2 = ((t + 2 < NT) ? (t + 2) : 0) * 64;

    // phase 1: read A(Mh0) + B(Nh0); stage B[t+1].h1 (other buffer)
#pragma unroll
    for (int mi = 0; mi < 4; ++mi) { RD_A(a[mi][0], cur, 0, mi, 0); RD_A(a[mi][1], cur, 0, mi, 1); }
#pragma unroll
    for (int nj = 0; nj < 2; ++nj) { RD_B(b[nj][0], cur, nj, 0); RD_B(b[nj][1], cur, nj, 1); }
    STAGE_B(nxt, 1, k1);
    gpu_barrier();
    asm volatile("s_waitcnt lgkmcnt(0)" ::: "memory");
    MFMA_QUAD(0, 0)
    gpu_barrier();

    // phase 2: read B(Nh1); stage A[t+2].h0 (A.h0 last read in ph1 -> safe)
#pragma unroll
    for (int nj = 2; nj < 4; ++nj) { RD_B(b[nj][0], cur, nj, 0); RD_B(b[nj][1], cur, nj, 1); }
    STAGE_A(cur, 0, k2);
    gpu_barrier();
    asm volatile("s_waitcnt lgkmcnt(0)" ::: "memory");
    MFMA_QUAD(0, 1)
    gpu_barrier();

    // phase 3: read A(Mh1); stage B[t+2].h0 (B last read in ph2 -> safe)
#pragma unroll
    for (int mi = 0; mi < 4; ++mi) { RD_A(a[mi][0], cur, 1, mi, 0); RD_A(a[mi][1], cur, 1, mi, 1); }
    STAGE_B(cur, 0, k2);
    gpu_barrier();
    asm volatile("s_waitcnt lgkmcnt(0)" ::: "memory");
    MFMA_QUAD(1, 0)
    gpu_barrier();

    // phase 4: stage A[t+2].h1 (A.h1 last read in ph3 -> safe); MFMA; counted vmcnt
    STAGE_A(cur, 1, k2);
    gpu_barrier();
    MFMA_QUAD(1, 1)
    asm volatile("s_waitcnt vmcnt(6)" ::: "memory");
    gpu_barrier();
  }

  // drain LDS-DMA before workgroup can exit (LDS may be reassigned)
  asm volatile("s_waitcnt vmcnt(0)" ::: "memory");

  // epilogue: C/D frag layout col=lane&15, row=(lane>>4)*4+reg
  const int crow0 = bm + wm * 64 + (lane >> 4) * 4;
  const int ccol0 = bn + wn * 64 + (lane & 15);
  if (OUTF32) {
    float* C = (float*)Cv;
    float bs[4];
#pragma unroll
    for (int j = 0; j < 4; ++j) bs[j] = bias ? bias[ccol0 + j * 16] : 0.0f;
#pragma unroll
    for (int i = 0; i < 8; ++i) {
      const int row = crow0 + (i >> 2) * 128 + (i & 3) * 16;
#pragma unroll
      for (int j = 0; j < 4; ++j) {
        const int col = ccol0 + j * 16;
#pragma unroll
        for (int r = 0; r < 4; ++r)
          C[(long)(row + r) * ldc + col] = acc[i][j][r] + bs[j];
      }
    }
  } else {
    unsigned short* C = (unsigned short*)Cv;
#pragma unroll
    for (int i = 0; i < 8; ++i) {
      const int row = crow0 + (i >> 2) * 128 + (i & 3) * 16;
#pragma unroll
      for (int j = 0; j < 4; ++j) {
        const int col = ccol0 + j * 16;
#pragma unroll
        for (int r = 0; r < 4; ++r)
          C[(long)(row + r) * ldc + col] = f2bf(acc[i][j][r]);
      }
    }
  }
#undef STAGE_A
#undef STAGE_B
#undef RD_A
#undef RD_B
#undef MFMA_QUAD
}

// ---------- kv partials: part[ck][bh][d][e] = sum_{n in chunk} k[n,d]*v[n,e] ----------
__global__ __launch_bounds__(256) void kv_partial_kernel(const bf16* __restrict__ qkv,
                                                         float* __restrict__ part) {
  __shared__ bf16 ks[256 * 64];
  __shared__ bf16 vs[256 * 64];
  const int bh = blockIdx.x;      // b*16 + h
  const int ck = blockIdx.y;      // n-chunk of 256
  const int b = bh >> 4, h = bh & 15;
  const int t = threadIdx.x;

  const long rowbase = (long)(b * 4096 + ck * 256) * 3072;
  const bf16* kg = qkv + rowbase + 1024 + h * 64;
  const bf16* vg = qkv + rowbase + 2048 + h * 64;
  const int lr = t >> 3;          // 0..31
  const int lc = (t & 7) * 8;
#pragma unroll
  for (int it = 0; it < 8; ++it) {
    const int r = lr + it * 32;
    *(s16x8*)&ks[r * 64 + lc] = *(const s16x8*)&kg[(long)r * 3072 + lc];
    *(s16x8*)&vs[r * 64 + lc] = *(const s16x8*)&vg[(long)r * 3072 + lc];
  }
  __syncthreads();

  const int d0 = (t >> 4) * 4;
  const int e0 = (t & 15) * 4;
  f32x4 acc[4] = {};
  for (int n = 0; n < 256; ++n) {
    s16x4 kd = *(const s16x4*)&ks[n * 64 + d0];
    s16x4 ve = *(const s16x4*)&vs[n * 64 + e0];
    float kf0 = bf2f(kd[0]), kf1 = bf2f(kd[1]), kf2 = bf2f(kd[2]), kf3 = bf2f(kd[3]);
    f32x4 vf;
    vf[0] = bf2f(ve[0]); vf[1] = bf2f(ve[1]); vf[2] = bf2f(ve[2]); vf[3] = bf2f(ve[3]);
#pragma unroll
    for (int j = 0; j < 4; ++j) {
      acc[0][j] += kf0 * vf[j];
      acc[1][j] += kf1 * vf[j];
      acc[2][j] += kf2 * vf[j];
      acc[3][j] += kf3 * vf[j];
    }
  }
  float* pb = part + (((long)ck * 64 + bh) << 12);
#pragma unroll
  for (int i = 0; i < 4; ++i)
    *(f32x4*)&pb[(d0 + i) * 64 + e0] = acc[i];
}

// ---------- reduce partials, apply scale, store TRANSPOSED: kvT[bh][e][d] ----------
__global__ __launch_bounds__(256) void kv_reduce_kernel(const float* __restrict__ part,
                                                        float* __restrict__ kvT) {
  const int idx = blockIdx.x * 256 + threadIdx.x;  // bh*4096 + d*64 + e
  float s = 0.0f;
#pragma unroll
  for (int ck = 0; ck < 16; ++ck) s += part[(long)ck * 262144 + idx];
  s *= 0.125f;                                      // D^-0.5, D=64
  const int bh = idx >> 12;
  const int d = (idx >> 6) & 63;
  const int e = idx & 63;
  kvT[((long)bh << 12) + e * 64 + d] = s;
}

// ---------- Mt_b[o, h*64+d] = sum_e Wo[o, h*64+e] * kv[b,h,d,e], bf16 out ----------
__global__ __launch_bounds__(256) void mt_kernel(const float* __restrict__ kvT,
                                                 const float* __restrict__ Wo,
                                                 unsigned short* __restrict__ Mt) {
  __shared__ float kvs[64 * 64];   // [e][d]
  __shared__ float wos[64 * 68];   // [o][e], padded stride 68
  const int oblk = blockIdx.x, h = blockIdx.y, b = blockIdx.z;
  const int t = threadIdx.x;

  const float* kvp = kvT + (((long)b * 16 + h) << 12);
#pragma unroll
  for (int i = 0; i < 16; ++i) kvs[t + i * 256] = kvp[t + i * 256];
  {
    const int r = t >> 2;
    const int c0 = (t & 3) * 16;
    const float* wop = Wo + (long)(oblk * 64 + r) * 1024 + h * 64 + c0;
#pragma unroll
    for (int j = 0; j < 16; j += 4)
      *(f32x4*)&wos[r * 68 + c0 + j] = *(const f32x4*)&wop[j];
  }
  __syncthreads();

  const int o = t >> 2;
  const int d0 = (t & 3) * 16;
  f32x4 acc[4] = {};
  for (int e = 0; e < 64; ++e) {
    const float w = wos[o * 68 + e];
    const float* kr = &kvs[e * 64 + d0];
#pragma unroll
    for (int q = 0; q < 4; ++q) {
      f32x4 kv4 = *(const f32x4*)&kr[q * 4];
#pragma unroll
      for (int j = 0; j < 4; ++j) acc[q][j] += w * kv4[j];
    }
  }
  unsigned short* mp = Mt + (long)b * 1048576 + (long)(oblk * 64 + o) * 1024 + h * 64 + d0;
#pragma unroll
  for (int q = 0; q < 4; ++q)
#pragma unroll
    for (int j = 0; j < 4; ++j) mp[q * 4 + j] = f2bf(acc[q][j]);
}

extern "C" void kernel_launch(void* const* d_in, const int* in_sizes, int n_in,
                              void* d_out, int out_size, void* d_ws, size_t ws_size,
                              hipStream_t stream) {
  const float* x  = (const float*)d_in[0];
  const float* Wq = (const float*)d_in[1];
  const float* Wk = (const float*)d_in[2];
  const float* Wv = (const float*)d_in[3];
  const float* Wo = (const float*)d_in[4];
  const float* bo = (const float*)d_in[5];
  float* out = (float*)d_out;

  char* ws = (char*)d_ws;
  bf16* xb    = (bf16*)(ws);
  float* part = (float*)(ws);
  float* kvT  = (float*)(ws + 16777216);
  unsigned short* Mt = (unsigned short*)(ws + 17825792);
  bf16* Wcat  = (bf16*)(ws + 33554432);
  bf16* qkv   = (bf16*)(ws + 39845888);

  // 1) casts
  cast_f32_to_bf16<<<8192, 256, 0, stream>>>(x, (unsigned short*)xb, 2097152);
  cast_f32_to_bf16<<<512, 256, 0, stream>>>(Wq, (unsigned short*)(Wcat), 131072);
  cast_f32_to_bf16<<<512, 256, 0, stream>>>(Wk, (unsigned short*)(Wcat + 1048576), 131072);
  cast_f32_to_bf16<<<512, 256, 0, stream>>>(Wv, (unsigned short*)(Wcat + 2097152), 131072);

  // 2) QKV GEMM: [16384,1024] x [3072,1024]^T -> qkv bf16 [16384,3072]
  gemm256<false><<<768, 512, 0, stream>>>(
      xb, 1024, Wcat, 1024, 0L, 4096, (void*)qkv, 3072, nullptr, 1024, 64);

  // 3) kv = scale * k^T v  (per b,h)
  kv_partial_kernel<<<dim3(64, 16), 256, 0, stream>>>(qkv, part);
  kv_reduce_kernel<<<1024, 256, 0, stream>>>(part, kvT);

  // 4) Mt_b = (blockdiag(kv_b) . Wo^T)^T in B^T layout, bf16
  mt_kernel<<<dim3(16, 16, 4), 256, 0, stream>>>(kvT, Wo, Mt);

  // 5) out = q . Mt_b^T + bo   (fp32 out, per-batch B matrix)
  gemm256<true><<<256, 512, 0, stream>>>(
      qkv, 3072, (const bf16*)Mt, 1024, 1048576L, 4096, (void*)out, 1024, bo, 1024, 64);
}

// Round 3
// 235.271 us; speedup vs baseline: 1.2548x; 1.0361x over previous
//
#include <hip/hip_runtime.h>
#include <hip/hip_bf16.h>

typedef __hip_bfloat16 bf16;
typedef float f32x4 __attribute__((ext_vector_type(4)));
typedef short s16x8 __attribute__((ext_vector_type(8)));
typedef short s16x4 __attribute__((ext_vector_type(4)));

typedef const __attribute__((address_space(1))) void* as1cvp;
typedef __attribute__((address_space(3))) void* as3vp;

__device__ __forceinline__ unsigned short f2bf(float f) {
  unsigned u = __float_as_uint(f);
  u += 0x7FFFu + ((u >> 16) & 1u);   // RNE
  return (unsigned short)(u >> 16);
}
__device__ __forceinline__ float bf2f(short s) {
  return __uint_as_float(((unsigned)(unsigned short)s) << 16);
}

__device__ __forceinline__ void gpu_barrier() {
  asm volatile("" ::: "memory");
  __builtin_amdgcn_s_barrier();
  asm volatile("" ::: "memory");
}

// ---------- fused cast fp32 -> bf16 for x, Wq, Wk, Wv ----------
__global__ __launch_bounds__(256) void cast_fused(const float* __restrict__ x,
                                                  const float* __restrict__ wq,
                                                  const float* __restrict__ wk,
                                                  const float* __restrict__ wv,
                                                  unsigned short* __restrict__ xb,
                                                  unsigned short* __restrict__ wcat) {
  int i = blockIdx.x * 256 + threadIdx.x;   // grid covers 2490368 groups of 8
  const float* src; unsigned short* dst; long off;
  if (i < 2097152) { src = x; dst = xb; off = (long)i * 8; }
  else {
    int j = i - 2097152;
    int seg = j >> 17;            // 131072 groups per W
    int jj = j & 131071;
    src = (seg == 0) ? wq : (seg == 1) ? wk : wv;
    dst = wcat + (long)seg * 1048576;
    off = (long)jj * 8;
  }
  f32x4 v0 = *(const f32x4*)&src[off];
  f32x4 v1 = *(const f32x4*)&src[off + 4];
  s16x8 o;
  o[0] = (short)f2bf(v0[0]); o[1] = (short)f2bf(v0[1]);
  o[2] = (short)f2bf(v0[2]); o[3] = (short)f2bf(v0[3]);
  o[4] = (short)f2bf(v1[0]); o[5] = (short)f2bf(v1[1]);
  o[6] = (short)f2bf(v1[2]); o[7] = (short)f2bf(v1[3]);
  *(s16x8*)&dst[off] = o;
}

// ================= 256x256 8-phase bf16 GEMM =================
// C[m,n] = sum_k A[m,k]*Bt[n,k].  8 waves (2M x 4N), BK=64, LDS 128 KiB dbuf.
// Phases per K-tile: (Mh0,kh0) (Mh0,kh1) (Mh1,kh0) (Mh1,kh1); B frags held in
// regs across phases.  Prefetch uniform 2 tiles ahead; two vmcnt(8) gates per
// tile, each waiting only on >=5-phase-old loads (ledger-verified).
template<bool OUTF32>
__global__ __launch_bounds__(512, 2) void gemm256(
    const bf16* __restrict__ A, int lda,
    const bf16* __restrict__ Bt, int ldb, long btStride, int rowsPerB,
    void* __restrict__ Cv, int ldc,
    const float* __restrict__ bias, int K, int ntiles)
{
  __shared__ char lds[131072];  // A: [buf0 32K][buf1 32K] ; B at +64K same layout

  const int nwg = gridDim.x;
  const int bid = blockIdx.x;
  const int wg  = (bid & 7) * (nwg >> 3) + (bid >> 3);  // XCD swizzle (nwg%8==0)
  const int bm = (wg / ntiles) * 256;   // n-fastest: per-XCD contiguous m-chunk
  const int bn = (wg % ntiles) * 256;

  const int tid  = threadIdx.x;
  const int wid  = tid >> 6;
  const int lane = tid & 63;
  const int wm = wid >> 2;        // 0..1
  const int wn = wid & 3;         // 0..3
  const int frow = lane & 15;
  const int fkb  = (lane >> 4) << 4;              // k-chunk byte offset
  const unsigned xorv = (unsigned)((lane & 7) << 4);

  const bf16* Bp = Bt + (btStride ? (long)(bm / rowsPerB) * btStride : 0);

  // staging source coords: LDS linear pos p -> global pos q = p ^ (((p>>7)&7)<<4)
  const int q0 = (tid * 16) ^ (((tid >> 3) & 7) << 4);
  const int q1 = (8192 + tid * 16) ^ (((tid >> 3) & 7) << 4);
  const int srow0 = q0 >> 7, scol0 = (q0 & 127) >> 1;
  const int srow1 = q1 >> 7, scol1 = (q1 & 127) >> 1;   // 64..127
  const bf16* ag0 = A  + (long)(bm + srow0) * lda + scol0;
  const bf16* ag1 = A  + (long)(bm + srow1) * lda + scol1;
  const bf16* bg0 = Bp + (long)(bn + srow0) * ldb + scol0;
  const bf16* bg1 = Bp + (long)(bn + srow1) * ldb + scol1;

#define STAGE_A(buf, half, kk) do {                                                  \
    __builtin_amdgcn_global_load_lds((as1cvp)(ag0 + (long)(half)*128*lda + (kk)),    \
        (as3vp)(lds + (buf)*32768 + (half)*16384 + wid*1024), 16, 0, 0);             \
    __builtin_amdgcn_global_load_lds((as1cvp)(ag1 + (long)(half)*128*lda + (kk)),    \
        (as3vp)(lds + (buf)*32768 + (half)*16384 + 8192 + wid*1024), 16, 0, 0);      \
  } while (0)
#define STAGE_B(buf, half, kk) do {                                                  \
    __builtin_amdgcn_global_load_lds((as1cvp)(bg0 + (long)(half)*128*ldb + (kk)),    \
        (as3vp)(lds + 65536 + (buf)*32768 + (half)*16384 + wid*1024), 16, 0, 0);     \
    __builtin_amdgcn_global_load_lds((as1cvp)(bg1 + (long)(half)*128*ldb + (kk)),    \
        (as3vp)(lds + 65536 + (buf)*32768 + (half)*16384 + 8192 + wid*1024), 16, 0, 0); \
  } while (0)

  const unsigned paBase = (unsigned)((wm * 64 + frow) * 128 + fkb);
  const unsigned pbBase = (unsigned)(((wn & 1) * 64 + frow) * 128 + fkb);
  const unsigned bHalf  = (unsigned)((wn >> 1) * 16384);

#define RD_A(dst, cur, Mh, mi, kh)                                                   \
  dst = *(const s16x8*)(lds + (cur)*32768 + (Mh)*16384 +                             \
                        ((paBase + (mi)*2048u + (kh)*64u) ^ xorv))
#define RD_B(dst, cur, nj, kh)                                                       \
  dst = *(const s16x8*)(lds + 65536 + (cur)*32768 + bHalf +                          \
                        ((pbBase + (nj)*2048u + (kh)*64u) ^ xorv))

#define MFMA16(base, bb)                                                             \
  __builtin_amdgcn_s_setprio(1);                                                     \
  _Pragma("unroll")                                                                  \
  for (int mi = 0; mi < 4; ++mi)                                                     \
    _Pragma("unroll")                                                                \
    for (int nj = 0; nj < 4; ++nj)                                                   \
      acc[(base) + mi][nj] = __builtin_amdgcn_mfma_f32_16x16x32_bf16(                \
          a[mi], bb[nj], acc[(base) + mi][nj], 0, 0, 0);                             \
  __builtin_amdgcn_s_setprio(0);

#define LGKM0 asm volatile("s_waitcnt lgkmcnt(0)" ::: "memory")
#define VM8   asm volatile("s_waitcnt vmcnt(8)" ::: "memory")

  f32x4 acc[8][4] = {};
  s16x8 a[4], b0[4], b1[4];
  const int NT = K >> 6;

  // ---- prologue: tiles 0 and 1, oldest-first ordering matching steady state
  STAGE_A(0, 0, 0); STAGE_B(0, 0, 0); STAGE_B(0, 1, 0);   // tile0 ph1/ph2 needs (6)
  STAGE_A(0, 1, 0);                                       // tile0 ph3/ph4 needs (2)
  {
    const int kk = (NT > 1) ? 64 : 0;
    STAGE_A(1, 0, kk); STAGE_B(1, 0, kk); STAGE_B(1, 1, kk);  // tile1 group (6)
  }
  VM8;            // drains first 6 -> tile0 ph1 ready
  gpu_barrier();

  for (int t = 0; t < NT; ++t) {
    const int cur = t & 1, nxt = cur ^ 1;
    const int k1 = ((t + 1 < NT) ? (t + 1) : 0) * 64;  // clamped dead loads
    const int k2 = ((t + 2 < NT) ? (t + 2) : 0) * 64;

    // ph1: A(Mh0,kh0)->a, B(kh0)->b0 ; stage A[t+1].h1 (region read t-1.ph4)
#pragma unroll
    for (int mi = 0; mi < 4; ++mi) RD_A(a[mi], cur, 0, mi, 0);
#pragma unroll
    for (int nj = 0; nj < 4; ++nj) RD_B(b0[nj], cur, nj, 0);
    STAGE_A(nxt, 1, k1);
    gpu_barrier(); LGKM0;
    MFMA16(0, b0)
    gpu_barrier();

    // ph2: A(Mh0,kh1)->a, B(kh1)->b1 ; gate: A[t].h1 (staged t-1.ph1) landed
#pragma unroll
    for (int mi = 0; mi < 4; ++mi) RD_A(a[mi], cur, 0, mi, 1);
#pragma unroll
    for (int nj = 0; nj < 4; ++nj) RD_B(b1[nj], cur, nj, 1);
    gpu_barrier(); LGKM0;
    MFMA16(0, b1)
    VM8;
    gpu_barrier();

    // ph3: A(Mh1,kh0)->a ; stage tile t+2 main group (A.h0, B.h0, B.h1)
#pragma unroll
    for (int mi = 0; mi < 4; ++mi) RD_A(a[mi], cur, 1, mi, 0);
    STAGE_A(cur, 0, k2); STAGE_B(cur, 0, k2); STAGE_B(cur, 1, k2);
    gpu_barrier(); LGKM0;
    MFMA16(4, b0)
    gpu_barrier();

    // ph4: A(Mh1,kh1)->a ; gate: tile t+1 main group (staged t-1.ph3) landed
#pragma unroll
    for (int mi = 0; mi < 4; ++mi) RD_A(a[mi], cur, 1, mi, 1);
    gpu_barrier(); LGKM0;
    MFMA16(4, b1)
    VM8;
    gpu_barrier();
  }

  // drain LDS-DMA before workgroup exit (LDS may be reassigned)
  asm volatile("s_waitcnt vmcnt(0)" ::: "memory");

  // epilogue: C/D frag layout col=lane&15, row=(lane>>4)*4+reg
  const int crow0 = bm + wm * 64 + (lane >> 4) * 4;
  const int ccol0 = bn + wn * 64 + (lane & 15);
  if (OUTF32) {
    float* C = (float*)Cv;
    float bs[4];
#pragma unroll
    for (int j = 0; j < 4; ++j) bs[j] = bias ? bias[ccol0 + j * 16] : 0.0f;
#pragma unroll
    for (int i = 0; i < 8; ++i) {
      const int row = crow0 + (i >> 2) * 128 + (i & 3) * 16;
#pragma unroll
      for (int j = 0; j < 4; ++j) {
        const int col = ccol0 + j * 16;
#pragma unroll
        for (int r = 0; r < 4; ++r)
          C[(long)(row + r) * ldc + col] = acc[i][j][r] + bs[j];
      }
    }
  } else {
    unsigned short* C = (unsigned short*)Cv;
#pragma unroll
    for (int i = 0; i < 8; ++i) {
      const int row = crow0 + (i >> 2) * 128 + (i & 3) * 16;
#pragma unroll
      for (int j = 0; j < 4; ++j) {
        const int col = ccol0 + j * 16;
#pragma unroll
        for (int r = 0; r < 4; ++r)
          C[(long)(row + r) * ldc + col] = f2bf(acc[i][j][r]);
      }
    }
  }
#undef STAGE_A
#undef STAGE_B
#undef RD_A
#undef RD_B
#undef MFMA16
#undef LGKM0
#undef VM8
}

// ---------- kv partials: part[ck][bh][d][e] = sum_{n in chunk} k[n,d]*v[n,e] ----------
__global__ __launch_bounds__(256) void kv_partial_kernel(const bf16* __restrict__ qkv,
                                                         float* __restrict__ part) {
  __shared__ bf16 ks[256 * 64];
  __shared__ bf16 vs[256 * 64];
  const int bh = blockIdx.x;      // b*16 + h
  const int ck = blockIdx.y;      // n-chunk of 256
  const int b = bh >> 4, h = bh & 15;
  const int t = threadIdx.x;

  const long rowbase = (long)(b * 4096 + ck * 256) * 3072;
  const bf16* kg = qkv + rowbase + 1024 + h * 64;
  const bf16* vg = qkv + rowbase + 2048 + h * 64;
  const int lr = t >> 3;          // 0..31
  const int lc = (t & 7) * 8;
#pragma unroll
  for (int it = 0; it < 8; ++it) {
    const int r = lr + it * 32;
    *(s16x8*)&ks[r * 64 + lc] = *(const s16x8*)&kg[(long)r * 3072 + lc];
    *(s16x8*)&vs[r * 64 + lc] = *(const s16x8*)&vg[(long)r * 3072 + lc];
  }
  __syncthreads();

  const int d0 = (t >> 4) * 4;
  const int e0 = (t & 15) * 4;
  f32x4 acc[4] = {};
  for (int n = 0; n < 256; ++n) {
    s16x4 kd = *(const s16x4*)&ks[n * 64 + d0];
    s16x4 ve = *(const s16x4*)&vs[n * 64 + e0];
    float kf0 = bf2f(kd[0]), kf1 = bf2f(kd[1]), kf2 = bf2f(kd[2]), kf3 = bf2f(kd[3]);
    f32x4 vf;
    vf[0] = bf2f(ve[0]); vf[1] = bf2f(ve[1]); vf[2] = bf2f(ve[2]); vf[3] = bf2f(ve[3]);
#pragma unroll
    for (int j = 0; j < 4; ++j) {
      acc[0][j] += kf0 * vf[j];
      acc[1][j] += kf1 * vf[j];
      acc[2][j] += kf2 * vf[j];
      acc[3][j] += kf3 * vf[j];
    }
  }
  float* pb = part + (((long)ck * 64 + bh) << 12);
#pragma unroll
  for (int i = 0; i < 4; ++i)
    *(f32x4*)&pb[(d0 + i) * 64 + e0] = acc[i];
}

// ---------- reduce partials, apply scale, store TRANSPOSED: kvT[bh][e][d] ----------
__global__ __launch_bounds__(256) void kv_reduce_kernel(const float* __restrict__ part,
                                                        float* __restrict__ kvT) {
  const int idx = blockIdx.x * 256 + threadIdx.x;  // bh*4096 + d*64 + e
  float s = 0.0f;
#pragma unroll
  for (int ck = 0; ck < 16; ++ck) s += part[(long)ck * 262144 + idx];
  s *= 0.125f;                                      // D^-0.5, D=64
  const int bh = idx >> 12;
  const int d = (idx >> 6) & 63;
  const int e = idx & 63;
  kvT[((long)bh << 12) + e * 64 + d] = s;
}

// ---------- Mt_b[o, h*64+d] = sum_e Wo[o, h*64+e] * kv[b,h,d,e], bf16 out ----------
__global__ __launch_bounds__(256) void mt_kernel(const float* __restrict__ kvT,
                                                 const float* __restrict__ Wo,
                                                 unsigned short* __restrict__ Mt) {
  __shared__ float kvs[64 * 64];   // [e][d]
  __shared__ float wos[64 * 68];   // [o][e], padded stride 68
  const int oblk = blockIdx.x, h = blockIdx.y, b = blockIdx.z;
  const int t = threadIdx.x;

  const float* kvp = kvT + (((long)b * 16 + h) << 12);
#pragma unroll
  for (int i = 0; i < 16; ++i) kvs[t + i * 256] = kvp[t + i * 256];
  {
    const int r = t >> 2;
    const int c0 = (t & 3) * 16;
    const float* wop = Wo + (long)(oblk * 64 + r) * 1024 + h * 64 + c0;
#pragma unroll
    for (int j = 0; j < 16; j += 4)
      *(f32x4*)&wos[r * 68 + c0 + j] = *(const f32x4*)&wop[j];
  }
  __syncthreads();

  const int o = t >> 2;
  const int d0 = (t & 3) * 16;
  f32x4 acc[4] = {};
  for (int e = 0; e < 64; ++e) {
    const float w = wos[o * 68 + e];
    const float* kr = &kvs[e * 64 + d0];
#pragma unroll
    for (int q = 0; q < 4; ++q) {
      f32x4 kv4 = *(const f32x4*)&kr[q * 4];
#pragma unroll
      for (int j = 0; j < 4; ++j) acc[q][j] += w * kv4[j];
    }
  }
  unsigned short* mp = Mt + (long)b * 1048576 + (long)(oblk * 64 + o) * 1024 + h * 64 + d0;
#pragma unroll
  for (int q = 0; q < 4; ++q)
#pragma unroll
    for (int j = 0; j < 4; ++j) mp[q * 4 + j] = f2bf(acc[q][j]);
}

extern "C" void kernel_launch(void* const* d_in, const int* in_sizes, int n_in,
                              void* d_out, int out_size, void* d_ws, size_t ws_size,
                              hipStream_t stream) {
  const float* x  = (const float*)d_in[0];
  const float* Wq = (const float*)d_in[1];
  const float* Wk = (const float*)d_in[2];
  const float* Wv = (const float*)d_in[3];
  const float* Wo = (const float*)d_in[4];
  const float* bo = (const float*)d_in[5];
  float* out = (float*)d_out;

  char* ws = (char*)d_ws;
  bf16* xb    = (bf16*)(ws);
  float* part = (float*)(ws);
  float* kvT  = (float*)(ws + 16777216);
  unsigned short* Mt = (unsigned short*)(ws + 17825792);
  bf16* Wcat  = (bf16*)(ws + 33554432);
  bf16* qkv   = (bf16*)(ws + 39845888);

  // 1) fused casts (x + Wq + Wk + Wv)
  cast_fused<<<9728, 256, 0, stream>>>(x, Wq, Wk, Wv, (unsigned short*)xb,
                                       (unsigned short*)Wcat);

  // 2) QKV GEMM: [16384,1024] x [3072,1024]^T -> qkv bf16 [16384,3072]
  gemm256<false><<<768, 512, 0, stream>>>(
      xb, 1024, Wcat, 1024, 0L, 4096, (void*)qkv, 3072, nullptr, 1024, 12);

  // 3) kv = scale * k^T v  (per b,h)
  kv_partial_kernel<<<dim3(64, 16), 256, 0, stream>>>(qkv, part);
  kv_reduce_kernel<<<1024, 256, 0, stream>>>(part, kvT);

  // 4) Mt_b = (blockdiag(kv_b) . Wo^T)^T in B^T layout, bf16
  mt_kernel<<<dim3(16, 16, 4), 256, 0, stream>>>(kvT, Wo, Mt);

  // 5) out = q . Mt_b^T + bo   (fp32 out, per-batch B matrix)
  gemm256<true><<<256, 512, 0, stream>>>(
      qkv, 3072, (const bf16*)Mt, 1024, 1048576L, 4096, (void*)out, 1024, bo, 1024, 4);
}